// Round 9
// baseline (309.380 us; speedup 1.0000x reference)
//
#include <hip/hip_runtime.h>

typedef unsigned short u16;
typedef unsigned int u32;
typedef __bf16 bf16x8 __attribute__((ext_vector_type(8)));
typedef short s16x4 __attribute__((ext_vector_type(4)));
typedef float f32x4 __attribute__((ext_vector_type(4)));

#define MFMA16(a,b,c) __builtin_amdgcn_mfma_f32_16x16x32_bf16((a),(b),(c),0,0,0)

// K=16 bf16 MFMA (v_mfma_f32_16x16x16_bf16): A/B = 4 bf16 (2 VGPR), C/D = 4 f32.
#if defined(__has_builtin)
#if __has_builtin(__builtin_amdgcn_mfma_f32_16x16x16bf16_1k)
#define MFMA1K(a,b,c) __builtin_amdgcn_mfma_f32_16x16x16bf16_1k((a),(b),(c),0,0,0)
#endif
#endif
#ifndef MFMA1K
__device__ __forceinline__ f32x4 mfma1k_asm(s16x4 a, s16x4 b, f32x4 c) {
    f32x4 d;
    asm volatile("v_mfma_f32_16x16x16_bf16 %0, %1, %2, %3"
                 : "=v"(d) : "v"(a), "v"(b), "0"(c));
    return d;
}
#define MFMA1K(a,b,c) mfma1k_asm((a),(b),(c))
#endif

__device__ __forceinline__ float b2f(u16 u) {
    u32 v = ((u32)u) << 16;
    return __builtin_bit_cast(float, v);
}
__device__ __forceinline__ u16 f2b(float f) {
    u32 u = __builtin_bit_cast(u32, f);
    u = u + 0x7FFFu + ((u >> 16) & 1u);   // RNE
    return (u16)(u >> 16);
}

// async global->LDS, 16B per lane. LDS dest is wave-uniform base + lane*16.
__device__ __forceinline__ void gload_lds16(const u16* g, u16* l) {
    __builtin_amdgcn_global_load_lds(
        (__attribute__((address_space(1))) void*)g,
        (__attribute__((address_space(3))) void*)l, 16, 0, 0);
}

// load 8 contiguous elements at element-offset `off`, as 8 bf16 (uint4).
__device__ __forceinline__ uint4 load8_bf16(const void* base, size_t off, int f32m) {
    if (f32m) {
        const float* p = (const float*)base + off;
        float4 a = *(const float4*)p;
        float4 b = *(const float4*)(p + 4);
        union { u16 u[8]; uint4 v; } t;
        t.u[0] = f2b(a.x); t.u[1] = f2b(a.y); t.u[2] = f2b(a.z); t.u[3] = f2b(a.w);
        t.u[4] = f2b(b.x); t.u[5] = f2b(b.y); t.u[6] = f2b(b.z); t.u[7] = f2b(b.w);
        return t.v;
    }
    return *(const uint4*)((const u16*)base + off);
}

// ---- per-block deterministic dtype vote (identical result in every block)
__device__ __forceinline__ int detect_f32(const u16* __restrict__ x) {
    __shared__ int cnt;
    if (threadIdx.x == 0) cnt = 0;
    __syncthreads();
    int my = ((x[2 * (threadIdx.x * 128)] >> 7) & 0xFF) >= 0x90;
    unsigned long long b = __ballot(my);
    if ((threadIdx.x & 63) == 0) atomicAdd(&cnt, (int)__popcll(b));
    __syncthreads();
    return cnt > 32;
}

// ---- transpose+convert tile: src[R][Cc] -> dst[Cc][R] bf16, 64x64 tile ----
__device__ __forceinline__ void transpose_tile(
    const void* __restrict__ src, u16* __restrict__ dst, int R, int Cc,
    int f32m, int bx, int by)
{
    __shared__ u16 tile[64 * 72];
    const int t = threadIdx.x;
    const int c0 = bx * 64, r0 = by * 64;
    #pragma unroll
    for (int i = 0; i < 2; ++i) {
        int ch = t + 256 * i;            // 512 chunks of 8
        int r = ch >> 3, c8 = (ch & 7) * 8;
        *(uint4*)&tile[r * 72 + c8] =
            load8_bf16(src, (size_t)(r0 + r) * Cc + c0 + c8, f32m);
    }
    __syncthreads();
    #pragma unroll
    for (int i = 0; i < 2; ++i) {
        int ch = t + 256 * i;
        int r = ch >> 3, c8 = (ch & 7) * 8;
        union { u16 u[8]; uint4 v; } tmp;
        #pragma unroll
        for (int j = 0; j < 8; ++j) tmp.u[j] = tile[(c8 + j) * 72 + r];
        *(uint4*)&dst[(size_t)(c0 + r) * R + r0 + c8] = tmp.v;
    }
}

// ---- fused preprocessing (unchanged) ----
__global__ __launch_bounds__(256) void k_prep(
    const u16* __restrict__ x, const void* __restrict__ Wa,
    const void* __restrict__ ba, const void* __restrict__ Wp,
    const void* __restrict__ bp,
    u16* __restrict__ WaT, u16* __restrict__ WpT, u16* __restrict__ Abf,
    u16* __restrict__ bac, u16* __restrict__ bpc, int* __restrict__ flag)
{
    const int f32m = detect_f32(x);
    int task = blockIdx.x;
    if (task < 768) {
        transpose_tile(Wa, WaT, 1024, 3072, f32m, task % 48, task / 48);
        return;
    }
    task -= 768;
    if (task < 256) {
        transpose_tile(Wp, WpT, 1024, 1024, f32m, task % 16, task / 16);
        return;
    }
    task -= 256;
    if (task < 4096) {
        if (!f32m) return;
        size_t i = ((size_t)task * 256 + threadIdx.x) * 8;
        const float* xf = (const float*)x;
        float4 a = *(const float4*)(xf + i);
        float4 b = *(const float4*)(xf + i + 4);
        union { u16 u[8]; uint4 v; } t;
        t.u[0] = f2b(a.x); t.u[1] = f2b(a.y); t.u[2] = f2b(a.z); t.u[3] = f2b(a.w);
        t.u[4] = f2b(b.x); t.u[5] = f2b(b.y); t.u[6] = f2b(b.z); t.u[7] = f2b(b.w);
        *(uint4*)(Abf + i) = t.v;
        return;
    }
    const int t = threadIdx.x;
    #pragma unroll
    for (int j = 0; j < 12; ++j) {
        int i = t + 256 * j;
        if (i < 3072) bac[i] = f32m ? f2b(((const float*)ba)[i]) : ((const u16*)ba)[i];
    }
    #pragma unroll
    for (int j = 0; j < 4; ++j) {
        int i = t + 256 * j;
        if (i < 1024) bpc[i] = f32m ? f2b(((const float*)bp)[i]) : ((const u16*)bp)[i];
    }
    if (t == 0) *flag = f32m;
}

// ======================= 8-phase 256-tile GEMM machinery ====================
// LDS granule swizzle (16B granules, 8 granules = one 64-elem bf16 row):
//   logical (row r, slot s) lives at LDS granule (r<<3) | (s ^ (r&7)).
// global_load_lds writes linearly -> stage granule g from GLOBAL granule
//   (r, (g&7) ^ (r&7)): both-sides-or-neither involution.

// stage one STRIDED 256x64 A-tile + STRIDED 128x64 B-tile (6 loads/thread)
__device__ __forceinline__ void stage_qkv(const u16* __restrict__ Asrc,
                                          const u16* __restrict__ Bsrc,
                                          u16* Asb, u16* Bsb, int wbase, int lane)
{
    #pragma unroll
    for (int i = 0; i < 4; ++i) {
        int gbase = wbase + 512 * i;
        int g = gbase | lane;
        int r = g >> 3, u = (g & 7) ^ (r & 7);
        gload_lds16(Asrc + (size_t)r * 1024 + u * 8, Asb + gbase * 8);
    }
    #pragma unroll
    for (int i = 0; i < 2; ++i) {
        int gbase = wbase + 512 * i;
        int g = gbase | lane;
        int r = g >> 3, u = (g & 7) ^ (r & 7);
        gload_lds16(Bsrc + (size_t)r * 1024 + u * 8, Bsb + gbase * 8);
    }
}

// stage one CONTIGUOUS-[256][64] A-tile + strided 128x64 B-tile (6 loads)
__device__ __forceinline__ void stage6(const u16* __restrict__ Asrc,
                                       const u16* __restrict__ Bsrc,
                                       u16* Asb, u16* Bsb, int wbase, int lane)
{
    #pragma unroll
    for (int i = 0; i < 4; ++i) {
        int gbase = wbase + 512 * i;
        int g = gbase | lane;
        int gg = (g & ~7) | ((g & 7) ^ ((g >> 3) & 7));
        gload_lds16(Asrc + gg * 8, Asb + gbase * 8);
    }
    #pragma unroll
    for (int i = 0; i < 2; ++i) {
        int gbase = wbase + 512 * i;
        int g = gbase | lane;
        int r = g >> 3, u = (g & 7) ^ (r & 7);
        gload_lds16(Bsrc + (size_t)r * 1024 + u * 8, Bsb + gbase * 8);
    }
}

__device__ __forceinline__ const u16* frag_ptr(const u16* base, int R, int sl) {
    int gr = (R << 3) | (sl ^ (R & 7));
    return base + gr * 8;
}

// ---------------- QKV GEMM: A[8192,1024] x Bt[3072,1024]^T + bias ----------
// 256x128 tile (round-8 lesson: the 256x256 version's 128 KB LDS -> 1
// block/CU with a 384-block grid = 1.5 rounds, half-idle second round).
// Here: 96 KB LDS, grid (32,24) = 768 blocks = exactly 3 balanced rounds.
// Same 8-phase counted-vmcnt(6) schedule as the proven proj kernel.
__global__ __launch_bounds__(512) void k_gemm_qkv(
    const void* __restrict__ x, const u16* __restrict__ Abf,
    const u16* __restrict__ Bt, const u16* __restrict__ bias,
    const int* __restrict__ flag,
    u16* __restrict__ Ql, u16* __restrict__ Kl, u16* __restrict__ Vl)
{
    __shared__ __align__(16) u16 As[2][16384];   // 64 KB (256x64 x2)
    __shared__ __align__(16) u16 Bs[2][8192];    // 32 KB (128x64 x2)
    const int t = threadIdx.x;
    const int lane = t & 63, w = t >> 6;
    const int wbase = t & ~63;
    const int quad = lane >> 4, m16 = lane & 15;
    const int wr = w >> 2, wc = w & 3;           // 2 x 4 wave grid (128x32/wave)
    const int m0 = blockIdx.x * 256, n0 = blockIdx.y * 128;
    const u16* A = (*flag) ? Abf : (const u16*)x;

    const u16* Atile = A + (size_t)m0 * 1024;
    const u16* Btile = Bt + (size_t)n0 * 1024;

    const f32x4 z = {0.f, 0.f, 0.f, 0.f};
    f32x4 acc[8][2];
    #pragma unroll
    for (int mi = 0; mi < 8; ++mi)
        #pragma unroll
        for (int ni = 0; ni < 2; ++ni) acc[mi][ni] = z;

    stage_qkv(Atile,      Btile,      &As[0][0], &Bs[0][0], wbase, lane);
    stage_qkv(Atile + 64, Btile + 64, &As[1][0], &Bs[1][0], wbase, lane);
    __builtin_amdgcn_sched_barrier(0);
    asm volatile("s_waitcnt vmcnt(6)" ::: "memory");
    __builtin_amdgcn_s_barrier();
    __builtin_amdgcn_sched_barrier(0);

    for (int kt = 0; kt < 16; ++kt) {
        const u16* Asb = &As[kt & 1][0];
        const u16* Bsb = &Bs[kt & 1][0];

        bf16x8 bfr[2][2];
        #pragma unroll
        for (int ni = 0; ni < 2; ++ni)
            #pragma unroll
            for (int kk = 0; kk < 2; ++kk)
                bfr[ni][kk] = *(const bf16x8*)frag_ptr(Bsb, wc * 32 + ni * 16 + m16, kk * 4 + quad);

        #pragma unroll
        for (int ph = 0; ph < 4; ++ph) {
            bf16x8 af[2][2];
            #pragma unroll
            for (int m2 = 0; m2 < 2; ++m2)
                #pragma unroll
                for (int kk = 0; kk < 2; ++kk)
                    af[m2][kk] = *(const bf16x8*)frag_ptr(
                        Asb, wr * 128 + (ph * 2 + m2) * 16 + m16, kk * 4 + quad);
            __builtin_amdgcn_s_setprio(1);
            #pragma unroll
            for (int m2 = 0; m2 < 2; ++m2)
                #pragma unroll
                for (int ni = 0; ni < 2; ++ni) {
                    acc[ph * 2 + m2][ni] = MFMA16(af[m2][0], bfr[ni][0], acc[ph * 2 + m2][ni]);
                    acc[ph * 2 + m2][ni] = MFMA16(af[m2][1], bfr[ni][1], acc[ph * 2 + m2][ni]);
                }
            __builtin_amdgcn_s_setprio(0);
        }

        __builtin_amdgcn_sched_barrier(0);
        __builtin_amdgcn_s_barrier();            // bar1: reads of this buf done
        if (kt < 14)
            stage_qkv(Atile + (kt + 2) * 64, Btile + (kt + 2) * 64,
                      (u16*)Asb, (u16*)Bsb, wbase, lane);
        __builtin_amdgcn_sched_barrier(0);
        if (kt < 14) asm volatile("s_waitcnt vmcnt(6)" ::: "memory");
        else         asm volatile("s_waitcnt vmcnt(0)" ::: "memory");
        __builtin_amdgcn_s_barrier();            // bar2
        __builtin_amdgcn_sched_barrier(0);
    }

    // epilogue: Q,K,V coalesced [BH][T][64]; block-uniform sec (128 | 1024)
    const int sec = n0 >> 10;
    const float qscale = (sec == 0) ? 0.18033688011112042f : 1.0f;  // 0.125*log2e
    u16* Outp = (sec == 0) ? Ql : (sec == 1) ? Kl : Vl;
    #pragma unroll
    for (int mi = 0; mi < 8; ++mi) {
        #pragma unroll
        for (int ni = 0; ni < 2; ++ni) {
            int gn = n0 + wc * 32 + ni * 16 + m16;
            int sn = gn & 1023;
            int h = sn >> 6, d = sn & 63;
            float bv = b2f(bias[gn]);
            #pragma unroll
            for (int v = 0; v < 4; ++v) {
                int gm = m0 + wr * 128 + mi * 16 + quad * 4 + v;
                int bb = gm >> 11, tt = gm & 2047;
                u16 o = f2b((acc[mi][ni][v] + bv) * qscale);
                size_t bh = (size_t)(bb * 16 + h);
                Outp[(bh * 2048 + tt) * 64 + d] = o;
            }
        }
    }
}

// ---------------- flash attention: block = (128 q rows, one (b,h)) ---------
// Round-9 restructure (LDS-pipe-bound per round-8 accounting):
//  * ni-fold: each bk (K) and va (V) fragment is read ONCE and feeds both
//    q-strips (per ni: QK both strips -> exp both -> PV both). LDS reads
//    per wave-tile: 32 b128 + 64 b64 -> 16 b128 + 32 b64 (halved).
//    Only transient regs grow; __launch_bounds__(256,4) pins the
//    128-VGPR / 4-blocks-per-CU point (round-2 cliff, enforced).
//  * Ks XOR-granule swizzle with DATA-permuted staging: K global loads
//    fetch the swizzled column (u = (c&7)^(r&7)); LDS writes are linear
//    (conflict-free); frag_ptr reads are 2-way (free). Replaces pad-80
//    (reads were 4-way, writes 8-way). Ks shrinks 20->16 KB.
__global__ __launch_bounds__(256, 4) void k_attn(
    u16* __restrict__ Ql, const u16* __restrict__ Kl, const u16* __restrict__ Vl)
{
    __shared__ __align__(16) u16 Ks[128 * 64];   // swizzled granules
    __shared__ u16 Vs[64 * 132];                 // [d][kv], stride 132
    const int t = threadIdx.x;
    const int lane = t & 63, w = t >> 6;
    const int quad = lane >> 4, m16 = lane & 15;
    const int g = blockIdx.x >> 6;
    const int p = g >> 2, r = g & 3;
    const int qb = (p == 0) ? 15 - r : (p == 1) ? 8 + r : (p == 2) ? 7 - r : r;
    const int bh = blockIdx.x & 63;              // XCD affinity (64 % 8 == 0)
    const int q0 = qb * 128;

    bf16x8 fq[2][2];
    #pragma unroll
    for (int s = 0; s < 2; ++s) {
        const u16* Qp = Ql + ((size_t)bh * 2048 + q0 + s * 64 + w * 16 + m16) * 64;
        fq[s][0] = *(const bf16x8*)&Qp[quad * 8];
        fq[s][1] = *(const bf16x8*)&Qp[32 + quad * 8];
    }

    const f32x4 z = {0.f, 0.f, 0.f, 0.f};
    f32x4 acco[2][4] = {{z, z, z, z}, {z, z, z, z}};   // O^T: q=m16, d=nd*16+quad*4+v
    f32x4 accl[2] = {z, z};                            // l via MFMA(ones, P^T)
    s16x4 ones4;
    #pragma unroll
    for (int j = 0; j < 4; ++j) ones4[j] = (short)0x3F80;   // bf16 1.0

    const int ktmax = qb;
    const u16* Kbase = Kl + (size_t)bh * 2048 * 64;
    const u16* Vbase = Vl + (size_t)bh * 2048 * 64;

    uint4 kreg[4], vreg[4];
    #pragma unroll
    for (int i = 0; i < 4; ++i) {
        int c = t + 256 * i;
        int rr = c >> 3;
        int ucol = ((c & 7) ^ (rr & 7)) * 8;      // pre-swizzled K column
        int col = (c & 7) * 8;
        kreg[i] = *(const uint4*)&Kbase[(size_t)rr * 64 + ucol];
        vreg[i] = *(const uint4*)&Vbase[(size_t)rr * 64 + col];
    }

    for (int kt = 0; kt <= ktmax; ++kt) {
        __syncthreads();
        #pragma unroll
        for (int i = 0; i < 4; ++i) {
            int c = t + 256 * i;
            int rr = c >> 3, col = (c & 7) * 8;
            *(uint4*)&Ks[c * 8] = kreg[i];        // linear granule write (free)
            union { u16 u[8]; uint4 v; } tv; tv.v = vreg[i];
            #pragma unroll
            for (int j = 0; j < 8; ++j)           // transpose into Vs[d][kv]
                Vs[(col + j) * 132 + rr] = tv.u[j];
        }
        __syncthreads();

        if (kt < ktmax) {   // prefetch next tile; overlaps compute
            #pragma unroll
            for (int i = 0; i < 4; ++i) {
                int c = t + 256 * i;
                int rr = c >> 3;
                int ucol = ((c & 7) ^ (rr & 7)) * 8;
                int col = (c & 7) * 8;
                kreg[i] = *(const uint4*)&Kbase[(size_t)((kt + 1) * 128 + rr) * 64 + ucol];
                vreg[i] = *(const uint4*)&Vbase[(size_t)((kt + 1) * 128 + rr) * 64 + col];
            }
        }

        const bool diag = (kt == ktmax);
        const int qg0 = q0 + w * 16 + m16;
        #pragma unroll
        for (int ni = 0; ni < 8; ++ni) {
            const int R = ni * 16 + m16;
            bf16x8 bk0 = *(const bf16x8*)frag_ptr(Ks, R, quad);
            bf16x8 bk1 = *(const bf16x8*)frag_ptr(Ks, R, 4 + quad);
            f32x4 as0 = z, as1 = z;
            __builtin_amdgcn_s_setprio(1);
            as0 = MFMA16(bk0, fq[0][0], as0);
            as1 = MFMA16(bk0, fq[1][0], as1);
            as0 = MFMA16(bk1, fq[0][1], as0);
            as1 = MFMA16(bk1, fq[1][1], as1);
            __builtin_amdgcn_s_setprio(0);

            s16x4 p0, p1;
            {
                union { __bf16 b[4]; s16x4 sv; } pa, pb;
                if (!diag) {
                    #pragma unroll
                    for (int v = 0; v < 4; ++v) {
                        pa.b[v] = (__bf16)__builtin_amdgcn_exp2f(as0[v]);
                        pb.b[v] = (__bf16)__builtin_amdgcn_exp2f(as1[v]);
                    }
                } else {
                    #pragma unroll
                    for (int v = 0; v < 4; ++v) {
                        int kv = kt * 128 + ni * 16 + quad * 4 + v;
                        float s0 = (kv > qg0)      ? -30000.0f : as0[v];
                        float s1 = (kv > qg0 + 64) ? -30000.0f : as1[v];
                        pa.b[v] = (__bf16)__builtin_amdgcn_exp2f(s0);
                        pb.b[v] = (__bf16)__builtin_amdgcn_exp2f(s1);
                    }
                }
                p0 = pa.sv; p1 = pb.sv;
            }

            __builtin_amdgcn_s_setprio(1);
            #pragma unroll
            for (int nd = 0; nd < 4; ++nd) {
                s16x4 va = *(const s16x4*)&Vs[(nd * 16 + m16) * 132 + ni * 16 + quad * 4];
                acco[0][nd] = MFMA1K(va, p0, acco[0][nd]);
                acco[1][nd] = MFMA1K(va, p1, acco[1][nd]);
            }
            accl[0] = MFMA1K(ones4, p0, accl[0]);
            accl[1] = MFMA1K(ones4, p1, accl[1]);
            __builtin_amdgcn_s_setprio(0);
        }
    }

    // write O back into Ql ([bh][t][64]): lane owns row q, 4 consecutive d
    #pragma unroll
    for (int s = 0; s < 2; ++s) {
        const int qg = q0 + s * 64 + w * 16 + m16;
        const float inv = 1.0f / fmaxf(accl[s][0], 1e-30f);
        u16* Orow = &Ql[((size_t)bh * 2048 + qg) * 64];
        #pragma unroll
        for (int nd = 0; nd < 4; ++nd) {
            union { u16 u[4]; uint2 uu; } o;
            #pragma unroll
            for (int v = 0; v < 4; ++v) o.u[v] = f2b(acco[s][nd][v] * inv);
            *(uint2*)&Orow[nd * 16 + quad * 4] = o.uu;
        }
    }
}

// ------- proj GEMM: Y (in Ql layout [bh][t][64]) x WpT[1024,1024]^T + bias -
// Unchanged from round 8 (256x128, 96 KB, 256 blocks = exactly 1/CU).
__global__ __launch_bounds__(512, 2) void k_gemm_proj(
    const u16* __restrict__ Yl, const u16* __restrict__ Bt, const u16* __restrict__ bias,
    const int* __restrict__ flag, void* __restrict__ Out)
{
    __shared__ __align__(16) u16 As[2][16384];   // 64 KB
    __shared__ __align__(16) u16 Bs[2][8192];    // 32 KB
    const int f32m = *flag;
    const int t = threadIdx.x;
    const int lane = t & 63, w = t >> 6;
    const int wbase = t & ~63;
    const int quad = lane >> 4, m16 = lane & 15;
    const int wr = w >> 2, wc = w & 3;
    const int m0 = blockIdx.x * 256, n0 = blockIdx.y * 128;
    const int bb = m0 >> 11, t0 = m0 & 2047;     // block-uniform (256 | 2048)

    const u16* Btile = Bt + (size_t)n0 * 1024;
    #define ABASE(KT) (Yl + ((size_t)(bb * 16 + (KT)) * 2048 + t0) * 64)

    const f32x4 z = {0.f, 0.f, 0.f, 0.f};
    f32x4 acc[8][2];
    #pragma unroll
    for (int mi = 0; mi < 8; ++mi)
        #pragma unroll
        for (int ni = 0; ni < 2; ++ni) acc[mi][ni] = z;

    stage6(ABASE(0), Btile,      &As[0][0], &Bs[0][0], wbase, lane);
    stage6(ABASE(1), Btile + 64, &As[1][0], &Bs[1][0], wbase, lane);
    __builtin_amdgcn_sched_barrier(0);
    asm volatile("s_waitcnt vmcnt(6)" ::: "memory");
    __builtin_amdgcn_s_barrier();
    __builtin_amdgcn_sched_barrier(0);

    for (int kt = 0; kt < 16; ++kt) {
        const u16* Asb = &As[kt & 1][0];
        const u16* Bsb = &Bs[kt & 1][0];

        bf16x8 bfr[2][2];
        #pragma unroll
        for (int ni = 0; ni < 2; ++ni)
            #pragma unroll
            for (int kk = 0; kk < 2; ++kk)
                bfr[ni][kk] = *(const bf16x8*)frag_ptr(Bsb, wc * 32 + ni * 16 + m16, kk * 4 + quad);

        #pragma unroll
        for (int ph = 0; ph < 4; ++ph) {
            bf16x8 af[2][2];
            #pragma unroll
            for (int m2 = 0; m2 < 2; ++m2)
                #pragma unroll
                for (int kk = 0; kk < 2; ++kk)
                    af[m2][kk] = *(const bf16x8*)frag_ptr(
                        Asb, wr * 128 + (ph * 2 + m2) * 16 + m16, kk * 4 + quad);
            __builtin_amdgcn_s_setprio(1);
            #pragma unroll
            for (int m2 = 0; m2 < 2; ++m2)
                #pragma unroll
                for (int ni = 0; ni < 2; ++ni) {
                    acc[ph * 2 + m2][ni] = MFMA16(af[m2][0], bfr[ni][0], acc[ph * 2 + m2][ni]);
                    acc[ph * 2 + m2][ni] = MFMA16(af[m2][1], bfr[ni][1], acc[ph * 2 + m2][ni]);
                }
            __builtin_amdgcn_s_setprio(0);
        }

        __builtin_amdgcn_sched_barrier(0);
        __builtin_amdgcn_s_barrier();            // bar1
        if (kt < 14)
            stage6(ABASE(kt + 2), Btile + (kt + 2) * 64,
                   (u16*)Asb, (u16*)Bsb, wbase, lane);
        __builtin_amdgcn_sched_barrier(0);
        if (kt < 14) asm volatile("s_waitcnt vmcnt(6)" ::: "memory");
        else         asm volatile("s_waitcnt vmcnt(0)" ::: "memory");
        __builtin_amdgcn_s_barrier();            // bar2
        __builtin_amdgcn_sched_barrier(0);
    }
    #undef ABASE

    #pragma unroll
    for (int mi = 0; mi < 8; ++mi) {
        #pragma unroll
        for (int ni = 0; ni < 2; ++ni) {
            int gn = n0 + wc * 32 + ni * 16 + m16;
            float bv = b2f(bias[gn]);
            #pragma unroll
            for (int v = 0; v < 4; ++v) {
                int gm = m0 + wr * 128 + mi * 16 + quad * 4 + v;
                float val = acc[mi][ni][v] + bv;
                if (f32m) ((float*)Out)[(size_t)gm * 1024 + gn] = val;
                else      ((u16*)Out)[(size_t)gm * 1024 + gn] = f2b(val);
            }
        }
    }
}

extern "C" void kernel_launch(void* const* d_in, const int* in_sizes, int n_in,
                              void* d_out, int out_size, void* d_ws, size_t ws_size,
                              hipStream_t stream)
{
    (void)in_sizes; (void)n_in; (void)out_size; (void)ws_size;
    const void* x  = d_in[0];   // [8192,1024]  f32 or bf16
    const void* Wa = d_in[1];   // [1024,3072]
    const void* ba = d_in[2];   // [3072]
    const void* Wp = d_in[3];   // [1024,1024]
    const void* bp = d_in[4];   // [1024]
    char* ws = (char*)d_ws;

    // ws: Q/O 16M @0 | K 16M @16M | V(row-major) 16M @32M | WpT 2M @48M | misc @50M
    u16* Ql  = (u16*)(ws + 0);
    u16* Kl  = (u16*)(ws + 16777216);
    u16* Vl  = (u16*)(ws + 33554432);
    u16* WpT = (u16*)(ws + 50331648);
    int* flag = (int*)(ws + 52428800);
    u16* bpc  = (u16*)(ws + 52428800 + 256);
    u16* bac  = (u16*)(ws + 52428800 + 256 + 2048);
    // d_out doubles as scratch until proj: WaT 6M @0 | Abf 16M @6M
    u16* WaT = (u16*)d_out;
    u16* Abf = (u16*)((char*)d_out + 6291456);

    k_prep<<<5121, 256, 0, stream>>>((const u16*)x, Wa, ba, Wp, bp,
                                     WaT, WpT, Abf, bac, bpc, flag);
    k_gemm_qkv<<<dim3(32, 24), 512, 0, stream>>>(x, Abf, WaT, bac, flag, Ql, Kl, Vl);
    k_attn<<<1024, 256, 0, stream>>>(Ql, Kl, Vl);
    k_gemm_proj<<<dim3(32, 8), 512, 0, stream>>>(Ql, WpT, bpc, flag, d_out);
}

// Round 10
// 282.172 us; speedup vs baseline: 1.0964x; 1.0964x over previous
//
#include <hip/hip_runtime.h>

typedef unsigned short u16;
typedef unsigned int u32;
typedef __bf16 bf16x8 __attribute__((ext_vector_type(8)));
typedef short s16x4 __attribute__((ext_vector_type(4)));
typedef float f32x4 __attribute__((ext_vector_type(4)));

#define MFMA16(a,b,c) __builtin_amdgcn_mfma_f32_16x16x32_bf16((a),(b),(c),0,0,0)

// K=16 bf16 MFMA (v_mfma_f32_16x16x16_bf16): A/B = 4 bf16 (2 VGPR), C/D = 4 f32.
#if defined(__has_builtin)
#if __has_builtin(__builtin_amdgcn_mfma_f32_16x16x16bf16_1k)
#define MFMA1K(a,b,c) __builtin_amdgcn_mfma_f32_16x16x16bf16_1k((a),(b),(c),0,0,0)
#endif
#endif
#ifndef MFMA1K
__device__ __forceinline__ f32x4 mfma1k_asm(s16x4 a, s16x4 b, f32x4 c) {
    f32x4 d;
    asm volatile("v_mfma_f32_16x16x16_bf16 %0, %1, %2, %3"
                 : "=v"(d) : "v"(a), "v"(b), "0"(c));
    return d;
}
#define MFMA1K(a,b,c) mfma1k_asm((a),(b),(c))
#endif

__device__ __forceinline__ float b2f(u16 u) {
    u32 v = ((u32)u) << 16;
    return __builtin_bit_cast(float, v);
}
__device__ __forceinline__ u16 f2b(float f) {
    u32 u = __builtin_bit_cast(u32, f);
    u = u + 0x7FFFu + ((u >> 16) & 1u);   // RNE
    return (u16)(u >> 16);
}

// async global->LDS, 16B per lane. LDS dest is wave-uniform base + lane*16.
__device__ __forceinline__ void gload_lds16(const u16* g, u16* l) {
    __builtin_amdgcn_global_load_lds(
        (__attribute__((address_space(1))) void*)g,
        (__attribute__((address_space(3))) void*)l, 16, 0, 0);
}

// load 8 contiguous elements at element-offset `off`, as 8 bf16 (uint4).
__device__ __forceinline__ uint4 load8_bf16(const void* base, size_t off, int f32m) {
    if (f32m) {
        const float* p = (const float*)base + off;
        float4 a = *(const float4*)p;
        float4 b = *(const float4*)(p + 4);
        union { u16 u[8]; uint4 v; } t;
        t.u[0] = f2b(a.x); t.u[1] = f2b(a.y); t.u[2] = f2b(a.z); t.u[3] = f2b(a.w);
        t.u[4] = f2b(b.x); t.u[5] = f2b(b.y); t.u[6] = f2b(b.z); t.u[7] = f2b(b.w);
        return t.v;
    }
    return *(const uint4*)((const u16*)base + off);
}

// ---- per-block deterministic dtype vote (identical result in every block)
__device__ __forceinline__ int detect_f32(const u16* __restrict__ x) {
    __shared__ int cnt;
    if (threadIdx.x == 0) cnt = 0;
    __syncthreads();
    int my = ((x[2 * (threadIdx.x * 128)] >> 7) & 0xFF) >= 0x90;
    unsigned long long b = __ballot(my);
    if ((threadIdx.x & 63) == 0) atomicAdd(&cnt, (int)__popcll(b));
    __syncthreads();
    return cnt > 32;
}

// ---- transpose+convert tile: src[R][Cc] -> dst[Cc][R] bf16, 64x64 tile ----
__device__ __forceinline__ void transpose_tile(
    const void* __restrict__ src, u16* __restrict__ dst, int R, int Cc,
    int f32m, int bx, int by)
{
    __shared__ u16 tile[64 * 72];
    const int t = threadIdx.x;
    const int c0 = bx * 64, r0 = by * 64;
    #pragma unroll
    for (int i = 0; i < 2; ++i) {
        int ch = t + 256 * i;            // 512 chunks of 8
        int r = ch >> 3, c8 = (ch & 7) * 8;
        *(uint4*)&tile[r * 72 + c8] =
            load8_bf16(src, (size_t)(r0 + r) * Cc + c0 + c8, f32m);
    }
    __syncthreads();
    #pragma unroll
    for (int i = 0; i < 2; ++i) {
        int ch = t + 256 * i;
        int r = ch >> 3, c8 = (ch & 7) * 8;
        union { u16 u[8]; uint4 v; } tmp;
        #pragma unroll
        for (int j = 0; j < 8; ++j) tmp.u[j] = tile[(c8 + j) * 72 + r];
        *(uint4*)&dst[(size_t)(c0 + r) * R + r0 + c8] = tmp.v;
    }
}

// ---- fused preprocessing (unchanged) ----
__global__ __launch_bounds__(256) void k_prep(
    const u16* __restrict__ x, const void* __restrict__ Wa,
    const void* __restrict__ ba, const void* __restrict__ Wp,
    const void* __restrict__ bp,
    u16* __restrict__ WaT, u16* __restrict__ WpT, u16* __restrict__ Abf,
    u16* __restrict__ bac, u16* __restrict__ bpc, int* __restrict__ flag)
{
    const int f32m = detect_f32(x);
    int task = blockIdx.x;
    if (task < 768) {
        transpose_tile(Wa, WaT, 1024, 3072, f32m, task % 48, task / 48);
        return;
    }
    task -= 768;
    if (task < 256) {
        transpose_tile(Wp, WpT, 1024, 1024, f32m, task % 16, task / 16);
        return;
    }
    task -= 256;
    if (task < 4096) {
        if (!f32m) return;
        size_t i = ((size_t)task * 256 + threadIdx.x) * 8;
        const float* xf = (const float*)x;
        float4 a = *(const float4*)(xf + i);
        float4 b = *(const float4*)(xf + i + 4);
        union { u16 u[8]; uint4 v; } t;
        t.u[0] = f2b(a.x); t.u[1] = f2b(a.y); t.u[2] = f2b(a.z); t.u[3] = f2b(a.w);
        t.u[4] = f2b(b.x); t.u[5] = f2b(b.y); t.u[6] = f2b(b.z); t.u[7] = f2b(b.w);
        *(uint4*)(Abf + i) = t.v;
        return;
    }
    const int t = threadIdx.x;
    #pragma unroll
    for (int j = 0; j < 12; ++j) {
        int i = t + 256 * j;
        if (i < 3072) bac[i] = f32m ? f2b(((const float*)ba)[i]) : ((const u16*)ba)[i];
    }
    #pragma unroll
    for (int j = 0; j < 4; ++j) {
        int i = t + 256 * j;
        if (i < 1024) bpc[i] = f32m ? f2b(((const float*)bp)[i]) : ((const u16*)bp)[i];
    }
    if (t == 0) *flag = f32m;
}

// ======================= 8-phase 256-tile GEMM machinery ====================
// LDS granule swizzle (16B granules, 8 granules = one 64-elem bf16 row):
//   logical (row r, slot s) lives at LDS granule (r<<3) | (s ^ (r&7)).
// global_load_lds writes linearly -> stage granule g from GLOBAL granule
//   (r, (g&7) ^ (r&7)): both-sides-or-neither involution.

// stage one STRIDED 256x64 A-tile + STRIDED 128x64 B-tile (6 loads/thread)
__device__ __forceinline__ void stage_qkv(const u16* __restrict__ Asrc,
                                          const u16* __restrict__ Bsrc,
                                          u16* Asb, u16* Bsb, int wbase, int lane)
{
    #pragma unroll
    for (int i = 0; i < 4; ++i) {
        int gbase = wbase + 512 * i;
        int g = gbase | lane;
        int r = g >> 3, u = (g & 7) ^ (r & 7);
        gload_lds16(Asrc + (size_t)r * 1024 + u * 8, Asb + gbase * 8);
    }
    #pragma unroll
    for (int i = 0; i < 2; ++i) {
        int gbase = wbase + 512 * i;
        int g = gbase | lane;
        int r = g >> 3, u = (g & 7) ^ (r & 7);
        gload_lds16(Bsrc + (size_t)r * 1024 + u * 8, Bsb + gbase * 8);
    }
}

// stage one CONTIGUOUS-[256][64] A-tile + strided 128x64 B-tile (6 loads)
__device__ __forceinline__ void stage6(const u16* __restrict__ Asrc,
                                       const u16* __restrict__ Bsrc,
                                       u16* Asb, u16* Bsb, int wbase, int lane)
{
    #pragma unroll
    for (int i = 0; i < 4; ++i) {
        int gbase = wbase + 512 * i;
        int g = gbase | lane;
        int gg = (g & ~7) | ((g & 7) ^ ((g >> 3) & 7));
        gload_lds16(Asrc + gg * 8, Asb + gbase * 8);
    }
    #pragma unroll
    for (int i = 0; i < 2; ++i) {
        int gbase = wbase + 512 * i;
        int g = gbase | lane;
        int r = g >> 3, u = (g & 7) ^ (r & 7);
        gload_lds16(Bsrc + (size_t)r * 1024 + u * 8, Bsb + gbase * 8);
    }
}

__device__ __forceinline__ const u16* frag_ptr(const u16* base, int R, int sl) {
    int gr = (R << 3) | (sl ^ (R & 7));
    return base + gr * 8;
}

// ---------------- QKV GEMM: A[8192,1024] x Bt[3072,1024]^T + bias ----------
// 256x128 tile, 96 KB LDS, grid (32,24) = 768 blocks = 3 balanced rounds.
// 8-phase counted-vmcnt(6) schedule.
__global__ __launch_bounds__(512) void k_gemm_qkv(
    const void* __restrict__ x, const u16* __restrict__ Abf,
    const u16* __restrict__ Bt, const u16* __restrict__ bias,
    const int* __restrict__ flag,
    u16* __restrict__ Ql, u16* __restrict__ Kl, u16* __restrict__ Vl)
{
    __shared__ __align__(16) u16 As[2][16384];   // 64 KB (256x64 x2)
    __shared__ __align__(16) u16 Bs[2][8192];    // 32 KB (128x64 x2)
    const int t = threadIdx.x;
    const int lane = t & 63, w = t >> 6;
    const int wbase = t & ~63;
    const int quad = lane >> 4, m16 = lane & 15;
    const int wr = w >> 2, wc = w & 3;           // 2 x 4 wave grid (128x32/wave)
    const int m0 = blockIdx.x * 256, n0 = blockIdx.y * 128;
    const u16* A = (*flag) ? Abf : (const u16*)x;

    const u16* Atile = A + (size_t)m0 * 1024;
    const u16* Btile = Bt + (size_t)n0 * 1024;

    const f32x4 z = {0.f, 0.f, 0.f, 0.f};
    f32x4 acc[8][2];
    #pragma unroll
    for (int mi = 0; mi < 8; ++mi)
        #pragma unroll
        for (int ni = 0; ni < 2; ++ni) acc[mi][ni] = z;

    stage_qkv(Atile,      Btile,      &As[0][0], &Bs[0][0], wbase, lane);
    stage_qkv(Atile + 64, Btile + 64, &As[1][0], &Bs[1][0], wbase, lane);
    __builtin_amdgcn_sched_barrier(0);
    asm volatile("s_waitcnt vmcnt(6)" ::: "memory");
    __builtin_amdgcn_s_barrier();
    __builtin_amdgcn_sched_barrier(0);

    for (int kt = 0; kt < 16; ++kt) {
        const u16* Asb = &As[kt & 1][0];
        const u16* Bsb = &Bs[kt & 1][0];

        bf16x8 bfr[2][2];
        #pragma unroll
        for (int ni = 0; ni < 2; ++ni)
            #pragma unroll
            for (int kk = 0; kk < 2; ++kk)
                bfr[ni][kk] = *(const bf16x8*)frag_ptr(Bsb, wc * 32 + ni * 16 + m16, kk * 4 + quad);

        #pragma unroll
        for (int ph = 0; ph < 4; ++ph) {
            bf16x8 af[2][2];
            #pragma unroll
            for (int m2 = 0; m2 < 2; ++m2)
                #pragma unroll
                for (int kk = 0; kk < 2; ++kk)
                    af[m2][kk] = *(const bf16x8*)frag_ptr(
                        Asb, wr * 128 + (ph * 2 + m2) * 16 + m16, kk * 4 + quad);
            __builtin_amdgcn_s_setprio(1);
            #pragma unroll
            for (int m2 = 0; m2 < 2; ++m2)
                #pragma unroll
                for (int ni = 0; ni < 2; ++ni) {
                    acc[ph * 2 + m2][ni] = MFMA16(af[m2][0], bfr[ni][0], acc[ph * 2 + m2][ni]);
                    acc[ph * 2 + m2][ni] = MFMA16(af[m2][1], bfr[ni][1], acc[ph * 2 + m2][ni]);
                }
            __builtin_amdgcn_s_setprio(0);
        }

        __builtin_amdgcn_sched_barrier(0);
        __builtin_amdgcn_s_barrier();            // bar1: reads of this buf done
        if (kt < 14)
            stage_qkv(Atile + (kt + 2) * 64, Btile + (kt + 2) * 64,
                      (u16*)Asb, (u16*)Bsb, wbase, lane);
        __builtin_amdgcn_sched_barrier(0);
        if (kt < 14) asm volatile("s_waitcnt vmcnt(6)" ::: "memory");
        else         asm volatile("s_waitcnt vmcnt(0)" ::: "memory");
        __builtin_amdgcn_s_barrier();            // bar2
        __builtin_amdgcn_sched_barrier(0);
    }

    // epilogue: Q,K,V coalesced [BH][T][64]; block-uniform sec (128 | 1024)
    const int sec = n0 >> 10;
    const float qscale = (sec == 0) ? 0.18033688011112042f : 1.0f;  // 0.125*log2e
    u16* Outp = (sec == 0) ? Ql : (sec == 1) ? Kl : Vl;
    #pragma unroll
    for (int mi = 0; mi < 8; ++mi) {
        #pragma unroll
        for (int ni = 0; ni < 2; ++ni) {
            int gn = n0 + wc * 32 + ni * 16 + m16;
            int sn = gn & 1023;
            int h = sn >> 6, d = sn & 63;
            float bv = b2f(bias[gn]);
            #pragma unroll
            for (int v = 0; v < 4; ++v) {
                int gm = m0 + wr * 128 + mi * 16 + quad * 4 + v;
                int bb = gm >> 11, tt = gm & 2047;
                u16 o = f2b((acc[mi][ni][v] + bv) * qscale);
                size_t bh = (size_t)(bb * 16 + h);
                Outp[(bh * 2048 + tt) * 64 + d] = o;
            }
        }
    }
}

// ---------------- flash attention: block = (128 q rows, one (b,h)) ---------
// ni-fold structure (halved LDS reads) + Ks granule swizzle, round-9.
// ROUND-9 LESSON: __launch_bounds__(256,4) made the allocator target 64
// VGPR -> ~150 MB scratch spill traffic/dispatch (WRITE_SIZE 59->207 MB),
// +28% dur. Plain (256) compiles this body to ~100-110 VGPR, no spill
// (ni-fold actually has a SMALLER live set than round-8's accs[8] form).
__global__ __launch_bounds__(256) void k_attn(
    u16* __restrict__ Ql, const u16* __restrict__ Kl, const u16* __restrict__ Vl)
{
    __shared__ __align__(16) u16 Ks[128 * 64];   // swizzled granules
    __shared__ u16 Vs[64 * 132];                 // [d][kv], stride 132
    const int t = threadIdx.x;
    const int lane = t & 63, w = t >> 6;
    const int quad = lane >> 4, m16 = lane & 15;
    const int g = blockIdx.x >> 6;
    const int p = g >> 2, r = g & 3;
    const int qb = (p == 0) ? 15 - r : (p == 1) ? 8 + r : (p == 2) ? 7 - r : r;
    const int bh = blockIdx.x & 63;              // XCD affinity (64 % 8 == 0)
    const int q0 = qb * 128;

    bf16x8 fq[2][2];
    #pragma unroll
    for (int s = 0; s < 2; ++s) {
        const u16* Qp = Ql + ((size_t)bh * 2048 + q0 + s * 64 + w * 16 + m16) * 64;
        fq[s][0] = *(const bf16x8*)&Qp[quad * 8];
        fq[s][1] = *(const bf16x8*)&Qp[32 + quad * 8];
    }

    const f32x4 z = {0.f, 0.f, 0.f, 0.f};
    f32x4 acco[2][4] = {{z, z, z, z}, {z, z, z, z}};   // O^T: q=m16, d=nd*16+quad*4+v
    f32x4 accl[2] = {z, z};                            // l via MFMA(ones, P^T)
    s16x4 ones4;
    #pragma unroll
    for (int j = 0; j < 4; ++j) ones4[j] = (short)0x3F80;   // bf16 1.0

    const int ktmax = qb;
    const u16* Kbase = Kl + (size_t)bh * 2048 * 64;
    const u16* Vbase = Vl + (size_t)bh * 2048 * 64;

    uint4 kreg[4], vreg[4];
    #pragma unroll
    for (int i = 0; i < 4; ++i) {
        int c = t + 256 * i;
        int rr = c >> 3;
        int ucol = ((c & 7) ^ (rr & 7)) * 8;      // pre-swizzled K column
        int col = (c & 7) * 8;
        kreg[i] = *(const uint4*)&Kbase[(size_t)rr * 64 + ucol];
        vreg[i] = *(const uint4*)&Vbase[(size_t)rr * 64 + col];
    }

    for (int kt = 0; kt <= ktmax; ++kt) {
        __syncthreads();
        #pragma unroll
        for (int i = 0; i < 4; ++i) {
            int c = t + 256 * i;
            int rr = c >> 3, col = (c & 7) * 8;
            *(uint4*)&Ks[c * 8] = kreg[i];        // linear granule write (free)
            union { u16 u[8]; uint4 v; } tv; tv.v = vreg[i];
            #pragma unroll
            for (int j = 0; j < 8; ++j)           // transpose into Vs[d][kv]
                Vs[(col + j) * 132 + rr] = tv.u[j];
        }
        __syncthreads();

        if (kt < ktmax) {   // prefetch next tile; overlaps compute
            #pragma unroll
            for (int i = 0; i < 4; ++i) {
                int c = t + 256 * i;
                int rr = c >> 3;
                int ucol = ((c & 7) ^ (rr & 7)) * 8;
                int col = (c & 7) * 8;
                kreg[i] = *(const uint4*)&Kbase[(size_t)((kt + 1) * 128 + rr) * 64 + ucol];
                vreg[i] = *(const uint4*)&Vbase[(size_t)((kt + 1) * 128 + rr) * 64 + col];
            }
        }

        const bool diag = (kt == ktmax);
        const int qg0 = q0 + w * 16 + m16;
        #pragma unroll
        for (int ni = 0; ni < 8; ++ni) {
            const int R = ni * 16 + m16;
            bf16x8 bk0 = *(const bf16x8*)frag_ptr(Ks, R, quad);
            bf16x8 bk1 = *(const bf16x8*)frag_ptr(Ks, R, 4 + quad);
            f32x4 as0 = z, as1 = z;
            __builtin_amdgcn_s_setprio(1);
            as0 = MFMA16(bk0, fq[0][0], as0);
            as1 = MFMA16(bk0, fq[1][0], as1);
            as0 = MFMA16(bk1, fq[0][1], as0);
            as1 = MFMA16(bk1, fq[1][1], as1);
            __builtin_amdgcn_s_setprio(0);

            s16x4 p0, p1;
            {
                union { __bf16 b[4]; s16x4 sv; } pa, pb;
                if (!diag) {
                    #pragma unroll
                    for (int v = 0; v < 4; ++v) {
                        pa.b[v] = (__bf16)__builtin_amdgcn_exp2f(as0[v]);
                        pb.b[v] = (__bf16)__builtin_amdgcn_exp2f(as1[v]);
                    }
                } else {
                    #pragma unroll
                    for (int v = 0; v < 4; ++v) {
                        int kv = kt * 128 + ni * 16 + quad * 4 + v;
                        float s0 = (kv > qg0)      ? -30000.0f : as0[v];
                        float s1 = (kv > qg0 + 64) ? -30000.0f : as1[v];
                        pa.b[v] = (__bf16)__builtin_amdgcn_exp2f(s0);
                        pb.b[v] = (__bf16)__builtin_amdgcn_exp2f(s1);
                    }
                }
                p0 = pa.sv; p1 = pb.sv;
            }

            __builtin_amdgcn_s_setprio(1);
            #pragma unroll
            for (int nd = 0; nd < 4; ++nd) {
                s16x4 va = *(const s16x4*)&Vs[(nd * 16 + m16) * 132 + ni * 16 + quad * 4];
                acco[0][nd] = MFMA1K(va, p0, acco[0][nd]);
                acco[1][nd] = MFMA1K(va, p1, acco[1][nd]);
            }
            accl[0] = MFMA1K(ones4, p0, accl[0]);
            accl[1] = MFMA1K(ones4, p1, accl[1]);
            __builtin_amdgcn_s_setprio(0);
        }
    }

    // write O back into Ql ([bh][t][64]): lane owns row q, 4 consecutive d
    #pragma unroll
    for (int s = 0; s < 2; ++s) {
        const int qg = q0 + s * 64 + w * 16 + m16;
        const float inv = 1.0f / fmaxf(accl[s][0], 1e-30f);
        u16* Orow = &Ql[((size_t)bh * 2048 + qg) * 64];
        #pragma unroll
        for (int nd = 0; nd < 4; ++nd) {
            union { u16 u[4]; uint2 uu; } o;
            #pragma unroll
            for (int v = 0; v < 4; ++v) o.u[v] = f2b(acco[s][nd][v] * inv);
            *(uint2*)&Orow[nd * 16 + quad * 4] = o.uu;
        }
    }
}

// ------- proj GEMM: Y (in Ql layout [bh][t][64]) x WpT[1024,1024]^T + bias -
// Unchanged (256x128, 96 KB, 256 blocks = exactly 1/CU).
__global__ __launch_bounds__(512, 2) void k_gemm_proj(
    const u16* __restrict__ Yl, const u16* __restrict__ Bt, const u16* __restrict__ bias,
    const int* __restrict__ flag, void* __restrict__ Out)
{
    __shared__ __align__(16) u16 As[2][16384];   // 64 KB
    __shared__ __align__(16) u16 Bs[2][8192];    // 32 KB
    const int f32m = *flag;
    const int t = threadIdx.x;
    const int lane = t & 63, w = t >> 6;
    const int wbase = t & ~63;
    const int quad = lane >> 4, m16 = lane & 15;
    const int wr = w >> 2, wc = w & 3;
    const int m0 = blockIdx.x * 256, n0 = blockIdx.y * 128;
    const int bb = m0 >> 11, t0 = m0 & 2047;     // block-uniform (256 | 2048)

    const u16* Btile = Bt + (size_t)n0 * 1024;
    #define ABASE(KT) (Yl + ((size_t)(bb * 16 + (KT)) * 2048 + t0) * 64)

    const f32x4 z = {0.f, 0.f, 0.f, 0.f};
    f32x4 acc[8][2];
    #pragma unroll
    for (int mi = 0; mi < 8; ++mi)
        #pragma unroll
        for (int ni = 0; ni < 2; ++ni) acc[mi][ni] = z;

    stage6(ABASE(0), Btile,      &As[0][0], &Bs[0][0], wbase, lane);
    stage6(ABASE(1), Btile + 64, &As[1][0], &Bs[1][0], wbase, lane);
    __builtin_amdgcn_sched_barrier(0);
    asm volatile("s_waitcnt vmcnt(6)" ::: "memory");
    __builtin_amdgcn_s_barrier();
    __builtin_amdgcn_sched_barrier(0);

    for (int kt = 0; kt < 16; ++kt) {
        const u16* Asb = &As[kt & 1][0];
        const u16* Bsb = &Bs[kt & 1][0];

        bf16x8 bfr[2][2];
        #pragma unroll
        for (int ni = 0; ni < 2; ++ni)
            #pragma unroll
            for (int kk = 0; kk < 2; ++kk)
                bfr[ni][kk] = *(const bf16x8*)frag_ptr(Bsb, wc * 32 + ni * 16 + m16, kk * 4 + quad);

        #pragma unroll
        for (int ph = 0; ph < 4; ++ph) {
            bf16x8 af[2][2];
            #pragma unroll
            for (int m2 = 0; m2 < 2; ++m2)
                #pragma unroll
                for (int kk = 0; kk < 2; ++kk)
                    af[m2][kk] = *(const bf16x8*)frag_ptr(
                        Asb, wr * 128 + (ph * 2 + m2) * 16 + m16, kk * 4 + quad);
            __builtin_amdgcn_s_setprio(1);
            #pragma unroll
            for (int m2 = 0; m2 < 2; ++m2)
                #pragma unroll
                for (int ni = 0; ni < 2; ++ni) {
                    acc[ph * 2 + m2][ni] = MFMA16(af[m2][0], bfr[ni][0], acc[ph * 2 + m2][ni]);
                    acc[ph * 2 + m2][ni] = MFMA16(af[m2][1], bfr[ni][1], acc[ph * 2 + m2][ni]);
                }
            __builtin_amdgcn_s_setprio(0);
        }

        __builtin_amdgcn_sched_barrier(0);
        __builtin_amdgcn_s_barrier();            // bar1
        if (kt < 14)
            stage6(ABASE(kt + 2), Btile + (kt + 2) * 64,
                   (u16*)Asb, (u16*)Bsb, wbase, lane);
        __builtin_amdgcn_sched_barrier(0);
        if (kt < 14) asm volatile("s_waitcnt vmcnt(6)" ::: "memory");
        else         asm volatile("s_waitcnt vmcnt(0)" ::: "memory");
        __builtin_amdgcn_s_barrier();            // bar2
        __builtin_amdgcn_sched_barrier(0);
    }
    #undef ABASE

    #pragma unroll
    for (int mi = 0; mi < 8; ++mi) {
        #pragma unroll
        for (int ni = 0; ni < 2; ++ni) {
            int gn = n0 + wc * 32 + ni * 16 + m16;
            float bv = b2f(bias[gn]);
            #pragma unroll
            for (int v = 0; v < 4; ++v) {
                int gm = m0 + wr * 128 + mi * 16 + quad * 4 + v;
                float val = acc[mi][ni][v] + bv;
                if (f32m) ((float*)Out)[(size_t)gm * 1024 + gn] = val;
                else      ((u16*)Out)[(size_t)gm * 1024 + gn] = f2b(val);
            }
        }
    }
}

extern "C" void kernel_launch(void* const* d_in, const int* in_sizes, int n_in,
                              void* d_out, int out_size, void* d_ws, size_t ws_size,
                              hipStream_t stream)
{
    (void)in_sizes; (void)n_in; (void)out_size; (void)ws_size;
    const void* x  = d_in[0];   // [8192,1024]  f32 or bf16
    const void* Wa = d_in[1];   // [1024,3072]
    const void* ba = d_in[2];   // [3072]
    const void* Wp = d_in[3];   // [1024,1024]
    const void* bp = d_in[4];   // [1024]
    char* ws = (char*)d_ws;

    // ws: Q/O 16M @0 | K 16M @16M | V(row-major) 16M @32M | WpT 2M @48M | misc @50M
    u16* Ql  = (u16*)(ws + 0);
    u16* Kl  = (u16*)(ws + 16777216);
    u16* Vl  = (u16*)(ws + 33554432);
    u16* WpT = (u16*)(ws + 50331648);
    int* flag = (int*)(ws + 52428800);
    u16* bpc  = (u16*)(ws + 52428800 + 256);
    u16* bac  = (u16*)(ws + 52428800 + 256 + 2048);
    // d_out doubles as scratch until proj: WaT 6M @0 | Abf 16M @6M
    u16* WaT = (u16*)d_out;
    u16* Abf = (u16*)((char*)d_out + 6291456);

    k_prep<<<5121, 256, 0, stream>>>((const u16*)x, Wa, ba, Wp, bp,
                                     WaT, WpT, Abf, bac, bpc, flag);
    k_gemm_qkv<<<dim3(32, 24), 512, 0, stream>>>(x, Abf, WaT, bac, flag, Ql, Kl, Vl);
    k_attn<<<1024, 256, 0, stream>>>(Ql, Kl, Vl);
    k_gemm_proj<<<dim3(32, 8), 512, 0, stream>>>(Ql, WpT, bpc, flag, d_out);
}